// Round 3
// baseline (36.695 us; speedup 1.0000x reference)
//
#include <hip/hip_runtime.h>
#include <hip/hip_bf16.h>

// B=16, N=128, F_IN=8, FC=256, H=256, E=N*(N-1)=16256, rows=B*E=260096, TAU=0.5
//
// Collapse: graph is broadcast from graph[0,0] -> every row into MLP1 is
// identical -> batchnorm over identical rows outputs exactly m1_beta (h-m==0).
// edge2node mean of identical rows -> identical node rows -> MLP2 outputs
// exactly m2_beta. Head input is one 512-vector [m2_beta,m2_beta] for ALL
// B*E rows: logits L[8] and prob=softmax(L) are computed ONCE.
// Per-row work is only g_graph = softmax((L + gumbel)/TAU).
//
// Dtypes: inputs float32; OUTPUT float32 (npz-size evidence: g_graph region
// incompressible f32, prob region repeated -> 7.8 MB compressed).

#define FC   256
#define HID  256
#define NOUT 8

// ---------------- Kernel A: one block, compute L[8] and prob[8] -> ws ---------
__global__ __launch_bounds__(1024) void head_kernel(
    const float* __restrict__ m2_beta,
    const float* __restrict__ Wi, const float* __restrict__ bi,
    const float* __restrict__ Wn, const float* __restrict__ bn_b,
    const float* __restrict__ f1W, const float* __restrict__ f1b,
    const float* __restrict__ f2W, const float* __restrict__ f2b,
    const float* __restrict__ f3W, const float* __restrict__ f3b,
    float* __restrict__ ws)   // ws[0..7] = L, ws[8..15] = prob
{
    __shared__ float sc[FC];        // m2_beta
    __shared__ float sh[HID];       // layer vector
    __shared__ float red[2][1024];  // k-split partials
    __shared__ float sL[NOUT];

    const int tid = threadIdx.x;
    const int t = tid & 255;   // output index
    const int c = tid >> 8;    // k-chunk 0..3 (64 k's each)

    if (tid < FC) sc[tid] = m2_beta[tid];
    __syncthreads();

    // ---- gate layer: ai = c512 @ Wi, an = c512 @ Wn, with c512=[beta,beta]
    {
        float ai = 0.f, an = 0.f;
        const int k0 = c * 64;
        #pragma unroll 4
        for (int k = k0; k < k0 + 64; ++k) {
            float ck = sc[k];
            ai += ck * (Wi[k * HID + t] + Wi[(k + FC) * HID + t]);
            an += ck * (Wn[k * HID + t] + Wn[(k + FC) * HID + t]);
        }
        red[0][tid] = ai;
        red[1][tid] = an;
    }
    __syncthreads();
    if (tid < FC) {
        float ai = red[0][t] + red[0][256 + t] + red[0][512 + t] + red[0][768 + t];
        float an = red[1][t] + red[1][256 + t] + red[1][512 + t] + red[1][768 + t];
        float iv = 1.f / (1.f + expf(-(ai + bi[t])));
        float nv = tanhf(an + bn_b[t]);
        sh[t] = (1.f - iv) * nv;          // hidden = (1-i)*n
    }
    __syncthreads();

    // ---- f1: o1 = relu(h @ f1W + f1b)
    {
        float a1 = 0.f;
        const int k0 = c * 64;
        #pragma unroll 4
        for (int k = k0; k < k0 + 64; ++k) a1 += sh[k] * f1W[k * HID + t];
        red[0][tid] = a1;
    }
    __syncthreads();
    float o1 = 0.f;
    if (tid < FC) {
        float a1 = red[0][t] + red[0][256 + t] + red[0][512 + t] + red[0][768 + t];
        o1 = fmaxf(a1 + f1b[t], 0.f);
    }
    __syncthreads();
    if (tid < FC) sh[t] = o1;
    __syncthreads();

    // ---- f2: o2 = relu(o1 @ f2W + f2b)
    {
        float a2 = 0.f;
        const int k0 = c * 64;
        #pragma unroll 4
        for (int k = k0; k < k0 + 64; ++k) a2 += sh[k] * f2W[k * HID + t];
        red[0][tid] = a2;
    }
    __syncthreads();
    float o2 = 0.f;
    if (tid < FC) {
        float a2 = red[0][t] + red[0][256 + t] + red[0][512 + t] + red[0][768 + t];
        o2 = fmaxf(a2 + f2b[t], 0.f);
    }
    __syncthreads();
    if (tid < FC) sh[t] = o2;
    __syncthreads();

    // ---- f3: L = o2 @ f3W + f3b   (f3W is [256, 8] row-major)
    {
        float* p = &red[0][0];   // reuse as [8][256]
        if (tid < FC) {
            float hv = sh[tid];
            #pragma unroll
            for (int j = 0; j < NOUT; ++j) p[j * 256 + tid] = hv * f3W[tid * NOUT + j];
        }
        __syncthreads();
        if (tid < NOUT) {
            float L = f3b[tid];
            for (int k = 0; k < FC; ++k) L += p[tid * 256 + k];
            sL[tid] = L;
            ws[tid] = L;
        }
    }
    __syncthreads();

    if (tid == 0) {
        float m = sL[0];
        #pragma unroll
        for (int j = 1; j < NOUT; ++j) m = fmaxf(m, sL[j]);
        float e[NOUT], s = 0.f;
        #pragma unroll
        for (int j = 0; j < NOUT; ++j) { e[j] = expf(sL[j] - m); s += e[j]; }
        float inv = 1.f / s;
        #pragma unroll
        for (int j = 0; j < NOUT; ++j) ws[NOUT + j] = e[j] * inv;
    }
}

// ---------------- Kernel B: per-row gumbel softmax + broadcast prob -----------
__global__ __launch_bounds__(256) void gumbel_kernel(
    const float* __restrict__ gn,  // [rows, 8] fp32
    const float* __restrict__ ws,  // L[8], prob[8]
    float* __restrict__ out,       // g_graph [rows,8] then prob [rows,8], fp32
    int rows)
{
    const int r = blockIdx.x * blockDim.x + threadIdx.x;
    if (r >= rows) return;

    float L[NOUT];
    #pragma unroll
    for (int j = 0; j < NOUT; ++j) L[j] = ws[j];

    const float4* gp = reinterpret_cast<const float4*>(gn + (size_t)r * NOUT);
    float4 g0 = gp[0];
    float4 g1 = gp[1];
    float g[NOUT] = {g0.x, g0.y, g0.z, g0.w, g1.x, g1.y, g1.z, g1.w};

    float z[NOUT];
    float m = -1e30f;
    #pragma unroll
    for (int j = 0; j < NOUT; ++j) {
        z[j] = (L[j] + g[j]) * 2.0f;   // 1/TAU = 2
        m = fmaxf(m, z[j]);
    }
    float s = 0.f;
    #pragma unroll
    for (int j = 0; j < NOUT; ++j) { z[j] = expf(z[j] - m); s += z[j]; }
    float inv = 1.f / s;

    float4* op = reinterpret_cast<float4*>(out + (size_t)r * NOUT);
    op[0] = make_float4(z[0] * inv, z[1] * inv, z[2] * inv, z[3] * inv);
    op[1] = make_float4(z[4] * inv, z[5] * inv, z[6] * inv, z[7] * inv);

    float4* pp = reinterpret_cast<float4*>(out + (size_t)(rows + r) * NOUT);
    pp[0] = make_float4(ws[8],  ws[9],  ws[10], ws[11]);
    pp[1] = make_float4(ws[12], ws[13], ws[14], ws[15]);
}

extern "C" void kernel_launch(void* const* d_in, const int* in_sizes, int n_in,
                              void* d_out, int out_size, void* d_ws, size_t ws_size,
                              hipStream_t stream) {
    // 0 graph, 1 rel_rec, 2 rel_send, 3 gumbel_noise,
    // 4 m1_W1, 5 m1_b1, 6 m1_W2, 7 m1_b2, 8 m1_g, 9 m1_beta,
    // 10 m2_W1, 11 m2_b1, 12 m2_W2, 13 m2_b2, 14 m2_g, 15 m2_beta,
    // 16 Wi, 17 bi, 18 Wn, 19 bn_b, 20 f1_W, 21 f1_b, 22 f2_W, 23 f2_b,
    // 24 f3_W, 25 f3_b
    const float* gumbel  = (const float*)d_in[3];
    const float* m2_beta = (const float*)d_in[15];
    const float* Wi      = (const float*)d_in[16];
    const float* bi      = (const float*)d_in[17];
    const float* Wn      = (const float*)d_in[18];
    const float* bn_b    = (const float*)d_in[19];
    const float* f1W     = (const float*)d_in[20];
    const float* f1b     = (const float*)d_in[21];
    const float* f2W     = (const float*)d_in[22];
    const float* f2b     = (const float*)d_in[23];
    const float* f3W     = (const float*)d_in[24];
    const float* f3b     = (const float*)d_in[25];

    const int rows = in_sizes[3] / NOUT;   // 260096
    float* ws = (float*)d_ws;

    head_kernel<<<1, 1024, 0, stream>>>(m2_beta, Wi, bi, Wn, bn_b,
                                        f1W, f1b, f2W, f2b, f3W, f3b, ws);

    const int threads = 256;
    const int blocks = (rows + threads - 1) / threads;
    gumbel_kernel<<<blocks, threads, 0, stream>>>(gumbel, ws, (float*)d_out, rows);
}

// Round 4
// 33.044 us; speedup vs baseline: 1.1105x; 1.1105x over previous
//
#include <hip/hip_runtime.h>

// B=16, N=128, F_IN=8, FC=256, H=256, E=N*(N-1)=16256, rows=B*E=260096, TAU=0.5
//
// Collapse (exact): graph is broadcast from graph[0,0] -> identical rows ->
// batchnorm over identical rows outputs exactly beta (h-mean == 0) for both
// MLPs. Head input is one 512-vector [m2_beta, m2_beta] for ALL B*E rows:
// logits L[8] and prob=softmax(L) are computed ONCE; per-row work is only
// g_graph = softmax((L + gumbel)/TAU).
//
// Dtypes: inputs float32, output float32 (validated round 3).
//
// Round-4 change: head kernel rebuilt for single-CU bandwidth — float4 weight
// loads (each element read once), 16-way k-chunk split + LDS reduce per layer.

#define FC   256
#define HID  256
#define NOUT 8

// ---------------- Kernel A: one block, compute L[8] and prob[8] -> ws ---------
__global__ __launch_bounds__(1024) void head_kernel(
    const float* __restrict__ m2_beta,
    const float* __restrict__ Wi, const float* __restrict__ bi,
    const float* __restrict__ Wn, const float* __restrict__ bn_b,
    const float* __restrict__ f1W, const float* __restrict__ f1b,
    const float* __restrict__ f2W, const float* __restrict__ f2b,
    const float* __restrict__ f3W, const float* __restrict__ f3b,
    float* __restrict__ ws)   // ws[0..7] = L, ws[8..15] = prob
{
    __shared__ float sc[2 * FC];      // head input vector [beta, beta]
    __shared__ float redA[16 * 256];  // k-chunk partials
    __shared__ float redB[16 * 256];
    __shared__ float sh[256];
    __shared__ float sh2[256];
    __shared__ float sL[NOUT];

    const int tid   = threadIdx.x;
    const int col4  = (tid & 63) * 4;   // 4 consecutive output cols
    const int chunk = tid >> 6;         // 16 k-chunks

    if (tid < 2 * FC) sc[tid] = m2_beta[tid & (FC - 1)];
    __syncthreads();

    // ---- gate layer: ai = c512 @ Wi, an = c512 @ Wn (Wi/Wn are [512][256])
    {
        float ai0=0,ai1=0,ai2=0,ai3=0, an0=0,an1=0,an2=0,an3=0;
        const int k0 = chunk * 32;
        #pragma unroll 8
        for (int k = k0; k < k0 + 32; ++k) {
            const float ck = sc[k];
            const float4 wi = *reinterpret_cast<const float4*>(&Wi[k * HID + col4]);
            const float4 wn = *reinterpret_cast<const float4*>(&Wn[k * HID + col4]);
            ai0 += ck * wi.x; ai1 += ck * wi.y; ai2 += ck * wi.z; ai3 += ck * wi.w;
            an0 += ck * wn.x; an1 += ck * wn.y; an2 += ck * wn.z; an3 += ck * wn.w;
        }
        *reinterpret_cast<float4*>(&redA[chunk * 256 + col4]) = make_float4(ai0, ai1, ai2, ai3);
        *reinterpret_cast<float4*>(&redB[chunk * 256 + col4]) = make_float4(an0, an1, an2, an3);
    }
    __syncthreads();
    if (tid < 256) {
        float ai = 0.f, an = 0.f;
        #pragma unroll
        for (int c = 0; c < 16; ++c) { ai += redA[c * 256 + tid]; an += redB[c * 256 + tid]; }
        const float iv = 1.f / (1.f + expf(-(ai + bi[tid])));
        const float nv = tanhf(an + bn_b[tid]);
        sh[tid] = (1.f - iv) * nv;     // hidden = (1-i)*n
    }
    __syncthreads();

    // ---- f1: o1 = relu(h @ f1W + f1b)
    {
        float a0=0,a1=0,a2=0,a3=0;
        const int k0 = chunk * 16;
        #pragma unroll 8
        for (int k = k0; k < k0 + 16; ++k) {
            const float hk = sh[k];
            const float4 w = *reinterpret_cast<const float4*>(&f1W[k * HID + col4]);
            a0 += hk * w.x; a1 += hk * w.y; a2 += hk * w.z; a3 += hk * w.w;
        }
        *reinterpret_cast<float4*>(&redA[chunk * 256 + col4]) = make_float4(a0, a1, a2, a3);
    }
    __syncthreads();
    if (tid < 256) {
        float a = 0.f;
        #pragma unroll
        for (int c = 0; c < 16; ++c) a += redA[c * 256 + tid];
        sh2[tid] = fmaxf(a + f1b[tid], 0.f);
    }
    __syncthreads();

    // ---- f2: o2 = relu(o1 @ f2W + f2b)
    {
        float a0=0,a1=0,a2=0,a3=0;
        const int k0 = chunk * 16;
        #pragma unroll 8
        for (int k = k0; k < k0 + 16; ++k) {
            const float hk = sh2[k];
            const float4 w = *reinterpret_cast<const float4*>(&f2W[k * HID + col4]);
            a0 += hk * w.x; a1 += hk * w.y; a2 += hk * w.z; a3 += hk * w.w;
        }
        *reinterpret_cast<float4*>(&redB[chunk * 256 + col4]) = make_float4(a0, a1, a2, a3);
    }
    __syncthreads();
    if (tid < 256) {
        float a = 0.f;
        #pragma unroll
        for (int c = 0; c < 16; ++c) a += redB[c * 256 + tid];
        sh[tid] = fmaxf(a + f2b[tid], 0.f);   // o2
    }
    __syncthreads();

    // ---- f3: L = o2 @ f3W + f3b   (f3W is [256][8])
    if (tid < 256) {
        const float o2 = sh[tid];
        const float4 wlo = *reinterpret_cast<const float4*>(&f3W[tid * NOUT]);
        const float4 whi = *reinterpret_cast<const float4*>(&f3W[tid * NOUT + 4]);
        redA[0*256+tid] = o2*wlo.x; redA[1*256+tid] = o2*wlo.y;
        redA[2*256+tid] = o2*wlo.z; redA[3*256+tid] = o2*wlo.w;
        redA[4*256+tid] = o2*whi.x; redA[5*256+tid] = o2*whi.y;
        redA[6*256+tid] = o2*whi.z; redA[7*256+tid] = o2*whi.w;
    }
    __syncthreads();
    for (int s = 128; s > 0; s >>= 1) {
        if (tid < s) {
            #pragma unroll
            for (int j = 0; j < NOUT; ++j) redA[j*256+tid] += redA[j*256+tid+s];
        }
        __syncthreads();
    }
    if (tid < NOUT) { sL[tid] = redA[tid * 256] + f3b[tid]; ws[tid] = sL[tid]; }
    __syncthreads();
    if (tid == 0) {
        float m = sL[0];
        #pragma unroll
        for (int j = 1; j < NOUT; ++j) m = fmaxf(m, sL[j]);
        float e[NOUT], s = 0.f;
        #pragma unroll
        for (int j = 0; j < NOUT; ++j) { e[j] = expf(sL[j] - m); s += e[j]; }
        const float inv = 1.f / s;
        #pragma unroll
        for (int j = 0; j < NOUT; ++j) ws[NOUT + j] = e[j] * inv;
    }
}

// ---------------- Kernel B: per-row gumbel softmax + broadcast prob -----------
__global__ __launch_bounds__(256) void gumbel_kernel(
    const float* __restrict__ gn,  // [rows, 8] fp32
    const float* __restrict__ ws,  // L[8], prob[8]
    float* __restrict__ out,       // g_graph [rows,8] then prob [rows,8], fp32
    int rows)
{
    const int r = blockIdx.x * blockDim.x + threadIdx.x;
    if (r >= rows) return;

    float L[NOUT];
    #pragma unroll
    for (int j = 0; j < NOUT; ++j) L[j] = ws[j];

    const float4* gp = reinterpret_cast<const float4*>(gn + (size_t)r * NOUT);
    const float4 g0 = gp[0];
    const float4 g1 = gp[1];
    const float g[NOUT] = {g0.x, g0.y, g0.z, g0.w, g1.x, g1.y, g1.z, g1.w};

    float z[NOUT];
    float m = -1e30f;
    #pragma unroll
    for (int j = 0; j < NOUT; ++j) {
        z[j] = (L[j] + g[j]) * 2.0f;   // 1/TAU = 2
        m = fmaxf(m, z[j]);
    }
    float s = 0.f;
    #pragma unroll
    for (int j = 0; j < NOUT; ++j) { z[j] = expf(z[j] - m); s += z[j]; }
    const float inv = 1.f / s;

    float4* op = reinterpret_cast<float4*>(out + (size_t)r * NOUT);
    op[0] = make_float4(z[0]*inv, z[1]*inv, z[2]*inv, z[3]*inv);
    op[1] = make_float4(z[4]*inv, z[5]*inv, z[6]*inv, z[7]*inv);

    float4* pp = reinterpret_cast<float4*>(out + (size_t)(rows + r) * NOUT);
    pp[0] = make_float4(ws[8],  ws[9],  ws[10], ws[11]);
    pp[1] = make_float4(ws[12], ws[13], ws[14], ws[15]);
}

extern "C" void kernel_launch(void* const* d_in, const int* in_sizes, int n_in,
                              void* d_out, int out_size, void* d_ws, size_t ws_size,
                              hipStream_t stream) {
    // 0 graph, 1 rel_rec, 2 rel_send, 3 gumbel_noise,
    // 4 m1_W1, 5 m1_b1, 6 m1_W2, 7 m1_b2, 8 m1_g, 9 m1_beta,
    // 10 m2_W1, 11 m2_b1, 12 m2_W2, 13 m2_b2, 14 m2_g, 15 m2_beta,
    // 16 Wi, 17 bi, 18 Wn, 19 bn_b, 20 f1_W, 21 f1_b, 22 f2_W, 23 f2_b,
    // 24 f3_W, 25 f3_b
    const float* gumbel  = (const float*)d_in[3];
    const float* m2_beta = (const float*)d_in[15];
    const float* Wi      = (const float*)d_in[16];
    const float* bi      = (const float*)d_in[17];
    const float* Wn      = (const float*)d_in[18];
    const float* bn_b    = (const float*)d_in[19];
    const float* f1W     = (const float*)d_in[20];
    const float* f1b     = (const float*)d_in[21];
    const float* f2W     = (const float*)d_in[22];
    const float* f2b     = (const float*)d_in[23];
    const float* f3W     = (const float*)d_in[24];
    const float* f3b     = (const float*)d_in[25];

    const int rows = in_sizes[3] / NOUT;   // 260096
    float* ws = (float*)d_ws;

    head_kernel<<<1, 1024, 0, stream>>>(m2_beta, Wi, bi, Wn, bn_b,
                                        f1W, f1b, f2W, f2b, f3W, f3b, ws);

    const int threads = 256;
    const int blocks = (rows + threads - 1) / threads;
    gumbel_kernel<<<blocks, threads, 0, stream>>>(gumbel, ws, (float*)d_out, rows);
}

// Round 5
// 25.387 us; speedup vs baseline: 1.4454x; 1.3016x over previous
//
#include <hip/hip_runtime.h>

// B=16, N=128, F_IN=8, FC=256, H=256, E=N*(N-1)=16256, rows=B*E=260096, TAU=0.5
//
// Collapse (exact): graph is broadcast from graph[0,0] -> identical rows ->
// batchnorm over identical rows outputs exactly beta for both MLPs. Head input
// is one 512-vector [m2_beta, m2_beta] for ALL B*E rows: logits L[8] and
// prob=softmax(L) are computed ONCE; per-row work is only
// g_graph = softmax((L + gumbel)/TAU).
//
// Round-5 change: gate layer (Wi+Wn = 1 MB, 2/3 of head traffic) split across
// 64 blocks (K1) with a [64][256]x2 partial buffer in ws; K2 (1 block) reduces
// and runs f1/f2/f3+softmax. 3 graph nodes total.

#define FC   256
#define HID  256
#define NOUT 8

// ws layout (floats):
//   [0..7]   L
//   [8..15]  prob
//   [64 .. 64+16384)          gate partials for Wi  [64][256]
//   [64+16384 .. 64+32768)    gate partials for Wn  [64][256]
#define WS_PI 64
#define WS_PN (64 + 64 * 256)

// ---------------- K1: gate partials, 64 blocks ---------------------------------
__global__ __launch_bounds__(256) void gate_partial(
    const float* __restrict__ m2_beta,
    const float* __restrict__ Wi, const float* __restrict__ Wn,
    float* __restrict__ ws)
{
    const int b = blockIdx.x;      // 0..63, k-range [8b, 8b+8)
    const int t = threadIdx.x;     // output col
    const int k0 = b * 8;
    float ai = 0.f, an = 0.f;
    #pragma unroll
    for (int i = 0; i < 8; ++i) {
        const int k = k0 + i;
        const float ck = m2_beta[k & (FC - 1)];   // c[k] = beta[k mod 256]
        ai += ck * Wi[k * HID + t];
        an += ck * Wn[k * HID + t];
    }
    ws[WS_PI + b * 256 + t] = ai;
    ws[WS_PN + b * 256 + t] = an;
}

// ---------------- K2: reduce + nonlin + f1 + f2 + f3 + softmax -----------------
__global__ __launch_bounds__(1024) void head_finish(
    const float* __restrict__ bi, const float* __restrict__ bn_b,
    const float* __restrict__ f1W, const float* __restrict__ f1b,
    const float* __restrict__ f2W, const float* __restrict__ f2b,
    const float* __restrict__ f3W, const float* __restrict__ f3b,
    float* __restrict__ ws)
{
    __shared__ float redA[16 * 256];
    __shared__ float redB[16 * 256];
    __shared__ float sh[256];
    __shared__ float sh2[256];
    __shared__ float sL[NOUT];

    const int tid   = threadIdx.x;
    const int col4  = (tid & 63) * 4;
    const int chunk = tid >> 6;        // 0..15
    const int t8    = tid & 255;
    const int c4    = tid >> 8;        // 0..3

    // ---- reduce gate partials: each (c4,t8) sums 16 of the 64 blocks
    {
        float ai = 0.f, an = 0.f;
        const int b0 = c4 * 16;
        #pragma unroll
        for (int b = 0; b < 16; ++b) {
            ai += ws[WS_PI + (b0 + b) * 256 + t8];
            an += ws[WS_PN + (b0 + b) * 256 + t8];
        }
        redA[c4 * 256 + t8] = ai;
        redB[c4 * 256 + t8] = an;
    }
    __syncthreads();
    if (tid < 256) {
        const float ai = redA[tid] + redA[256 + tid] + redA[512 + tid] + redA[768 + tid];
        const float an = redB[tid] + redB[256 + tid] + redB[512 + tid] + redB[768 + tid];
        const float iv = 1.f / (1.f + expf(-(ai + bi[tid])));
        const float nv = tanhf(an + bn_b[tid]);
        sh[tid] = (1.f - iv) * nv;     // hidden = (1-i)*n
    }
    __syncthreads();

    // ---- f1: o1 = relu(h @ f1W + f1b)
    {
        float a0=0,a1=0,a2=0,a3=0;
        const int k0 = chunk * 16;
        #pragma unroll 8
        for (int k = k0; k < k0 + 16; ++k) {
            const float hk = sh[k];
            const float4 w = *reinterpret_cast<const float4*>(&f1W[k * HID + col4]);
            a0 += hk * w.x; a1 += hk * w.y; a2 += hk * w.z; a3 += hk * w.w;
        }
        *reinterpret_cast<float4*>(&redA[chunk * 256 + col4]) = make_float4(a0, a1, a2, a3);
    }
    __syncthreads();
    if (tid < 256) {
        float a = 0.f;
        #pragma unroll
        for (int c = 0; c < 16; ++c) a += redA[c * 256 + tid];
        sh2[tid] = fmaxf(a + f1b[tid], 0.f);
    }
    __syncthreads();

    // ---- f2: o2 = relu(o1 @ f2W + f2b)
    {
        float a0=0,a1=0,a2=0,a3=0;
        const int k0 = chunk * 16;
        #pragma unroll 8
        for (int k = k0; k < k0 + 16; ++k) {
            const float hk = sh2[k];
            const float4 w = *reinterpret_cast<const float4*>(&f2W[k * HID + col4]);
            a0 += hk * w.x; a1 += hk * w.y; a2 += hk * w.z; a3 += hk * w.w;
        }
        *reinterpret_cast<float4*>(&redB[chunk * 256 + col4]) = make_float4(a0, a1, a2, a3);
    }
    __syncthreads();
    if (tid < 256) {
        float a = 0.f;
        #pragma unroll
        for (int c = 0; c < 16; ++c) a += redB[c * 256 + tid];
        sh[tid] = fmaxf(a + f2b[tid], 0.f);   // o2
    }
    __syncthreads();

    // ---- f3: L = o2 @ f3W + f3b   (f3W is [256][8])
    if (tid < 256) {
        const float o2 = sh[tid];
        const float4 wlo = *reinterpret_cast<const float4*>(&f3W[tid * NOUT]);
        const float4 whi = *reinterpret_cast<const float4*>(&f3W[tid * NOUT + 4]);
        redA[0*256+tid] = o2*wlo.x; redA[1*256+tid] = o2*wlo.y;
        redA[2*256+tid] = o2*wlo.z; redA[3*256+tid] = o2*wlo.w;
        redA[4*256+tid] = o2*whi.x; redA[5*256+tid] = o2*whi.y;
        redA[6*256+tid] = o2*whi.z; redA[7*256+tid] = o2*whi.w;
    }
    __syncthreads();
    for (int s = 128; s > 0; s >>= 1) {
        if (tid < s) {
            #pragma unroll
            for (int j = 0; j < NOUT; ++j) redA[j*256+tid] += redA[j*256+tid+s];
        }
        __syncthreads();
    }
    if (tid < NOUT) { sL[tid] = redA[tid * 256] + f3b[tid]; ws[tid] = sL[tid]; }
    __syncthreads();
    if (tid == 0) {
        float m = sL[0];
        #pragma unroll
        for (int j = 1; j < NOUT; ++j) m = fmaxf(m, sL[j]);
        float e[NOUT], s = 0.f;
        #pragma unroll
        for (int j = 0; j < NOUT; ++j) { e[j] = expf(sL[j] - m); s += e[j]; }
        const float inv = 1.f / s;
        #pragma unroll
        for (int j = 0; j < NOUT; ++j) ws[NOUT + j] = e[j] * inv;
    }
}

// ---------------- K3: per-row gumbel softmax + broadcast prob ------------------
__global__ __launch_bounds__(256) void gumbel_kernel(
    const float* __restrict__ gn,  // [rows, 8] fp32
    const float* __restrict__ ws,  // L[8], prob[8]
    float* __restrict__ out,       // g_graph [rows,8] then prob [rows,8], fp32
    int rows)
{
    const int r = blockIdx.x * blockDim.x + threadIdx.x;
    if (r >= rows) return;

    float L[NOUT];
    #pragma unroll
    for (int j = 0; j < NOUT; ++j) L[j] = ws[j];

    const float4* gp = reinterpret_cast<const float4*>(gn + (size_t)r * NOUT);
    const float4 g0 = gp[0];
    const float4 g1 = gp[1];
    const float g[NOUT] = {g0.x, g0.y, g0.z, g0.w, g1.x, g1.y, g1.z, g1.w};

    float z[NOUT];
    float m = -1e30f;
    #pragma unroll
    for (int j = 0; j < NOUT; ++j) {
        z[j] = (L[j] + g[j]) * 2.0f;   // 1/TAU = 2
        m = fmaxf(m, z[j]);
    }
    float s = 0.f;
    #pragma unroll
    for (int j = 0; j < NOUT; ++j) { z[j] = expf(z[j] - m); s += z[j]; }
    const float inv = 1.f / s;

    float4* op = reinterpret_cast<float4*>(out + (size_t)r * NOUT);
    op[0] = make_float4(z[0]*inv, z[1]*inv, z[2]*inv, z[3]*inv);
    op[1] = make_float4(z[4]*inv, z[5]*inv, z[6]*inv, z[7]*inv);

    float4* pp = reinterpret_cast<float4*>(out + (size_t)(rows + r) * NOUT);
    pp[0] = make_float4(ws[8],  ws[9],  ws[10], ws[11]);
    pp[1] = make_float4(ws[12], ws[13], ws[14], ws[15]);
}

extern "C" void kernel_launch(void* const* d_in, const int* in_sizes, int n_in,
                              void* d_out, int out_size, void* d_ws, size_t ws_size,
                              hipStream_t stream) {
    // 0 graph, 1 rel_rec, 2 rel_send, 3 gumbel_noise,
    // 4 m1_W1, 5 m1_b1, 6 m1_W2, 7 m1_b2, 8 m1_g, 9 m1_beta,
    // 10 m2_W1, 11 m2_b1, 12 m2_W2, 13 m2_b2, 14 m2_g, 15 m2_beta,
    // 16 Wi, 17 bi, 18 Wn, 19 bn_b, 20 f1_W, 21 f1_b, 22 f2_W, 23 f2_b,
    // 24 f3_W, 25 f3_b
    const float* gumbel  = (const float*)d_in[3];
    const float* m2_beta = (const float*)d_in[15];
    const float* Wi      = (const float*)d_in[16];
    const float* bi      = (const float*)d_in[17];
    const float* Wn      = (const float*)d_in[18];
    const float* bn_b    = (const float*)d_in[19];
    const float* f1W     = (const float*)d_in[20];
    const float* f1b     = (const float*)d_in[21];
    const float* f2W     = (const float*)d_in[22];
    const float* f2b     = (const float*)d_in[23];
    const float* f3W     = (const float*)d_in[24];
    const float* f3b     = (const float*)d_in[25];

    const int rows = in_sizes[3] / NOUT;   // 260096
    float* ws = (float*)d_ws;

    gate_partial<<<64, 256, 0, stream>>>(m2_beta, Wi, Wn, ws);
    head_finish<<<1, 1024, 0, stream>>>(bi, bn_b, f1W, f1b, f2W, f2b, f3W, f3b, ws);

    const int threads = 256;
    const int blocks = (rows + threads - 1) / threads;
    gumbel_kernel<<<blocks, threads, 0, stream>>>(gumbel, ws, (float*)d_out, rows);
}

// Round 6
// 23.533 us; speedup vs baseline: 1.5593x; 1.0788x over previous
//
#include <hip/hip_runtime.h>

// B=16, N=128, F_IN=8, FC=256, H=256, E=N*(N-1)=16256, rows=B*E=260096, TAU=0.5
//
// Collapse (exact): graph is broadcast from graph[0,0] -> identical rows ->
// batchnorm over identical rows outputs exactly beta for both MLPs. Head input
// is one 512-vector [m2_beta, m2_beta] for ALL B*E rows: logits L[8] and
// prob=softmax(L) are computed ONCE; per-row work is only
// g_graph = softmax((L + gumbel)/TAU).
//
// Round-6: no single-CU bulk reads anywhere. Each 256-wide matvec output is
// column-sliced across 64 blocks (4 cols/block, one float4 of W per thread,
// shuffle+LDS reduce). Chain: gate(64) -> f1(64) -> f2(64) -> f3+softmax(1)
// -> gumbel(1016). 5 dependent dispatches, no inter-block spin sync.

#define FC   256
#define HID  256
#define NOUT 8

// ws layout (floats): [0..7]=L, [8..15]=prob, [64..319]=h, [320..575]=o1,
// [576..831]=o2
#define WS_H  64
#define WS_O1 320
#define WS_O2 576

// ---- K1: gate layer, h = (1-sigmoid(c@Wi+bi)) * tanh(c@Wn+bn_b) -------------
// c[k] = beta[k mod 256] for k in [0,512); fold rows k and k+256.
__global__ __launch_bounds__(256) void gate_cols(
    const float* __restrict__ beta,
    const float* __restrict__ Wi, const float* __restrict__ Wn,
    const float* __restrict__ bi, const float* __restrict__ bn_b,
    float* __restrict__ ws)
{
    const int b  = blockIdx.x;     // 0..63
    const int t  = threadIdx.x;    // 0..255 (= k mod 256)
    const int c0 = b * 4;

    const float ck = beta[t];
    const float4 wi0 = *reinterpret_cast<const float4*>(&Wi[(size_t)t * HID + c0]);
    const float4 wi1 = *reinterpret_cast<const float4*>(&Wi[(size_t)(t + 256) * HID + c0]);
    const float4 wn0 = *reinterpret_cast<const float4*>(&Wn[(size_t)t * HID + c0]);
    const float4 wn1 = *reinterpret_cast<const float4*>(&Wn[(size_t)(t + 256) * HID + c0]);

    float v[8];
    v[0] = ck * (wi0.x + wi1.x); v[1] = ck * (wi0.y + wi1.y);
    v[2] = ck * (wi0.z + wi1.z); v[3] = ck * (wi0.w + wi1.w);
    v[4] = ck * (wn0.x + wn1.x); v[5] = ck * (wn0.y + wn1.y);
    v[6] = ck * (wn0.z + wn1.z); v[7] = ck * (wn0.w + wn1.w);

    #pragma unroll
    for (int off = 32; off > 0; off >>= 1) {
        #pragma unroll
        for (int j = 0; j < 8; ++j) v[j] += __shfl_xor(v[j], off, 64);
    }

    __shared__ float lds[4][8];
    const int lane = t & 63, wid = t >> 6;
    if (lane == 0) {
        #pragma unroll
        for (int j = 0; j < 8; ++j) lds[wid][j] = v[j];
    }
    __syncthreads();
    if (t < 4) {
        const float ai = lds[0][t] + lds[1][t] + lds[2][t] + lds[3][t];
        const float an = lds[0][4 + t] + lds[1][4 + t] + lds[2][4 + t] + lds[3][4 + t];
        const int c = c0 + t;
        const float iv = 1.f / (1.f + expf(-(ai + bi[c])));
        const float nv = tanhf(an + bn_b[c]);
        ws[WS_H + c] = (1.f - iv) * nv;   // hidden = (1-i)*n
    }
}

// ---- K2/K3: y[c0..c0+4) = relu(x @ W + bias), 64 blocks ----------------------
__global__ __launch_bounds__(256) void fc_cols(
    const float* __restrict__ W, const float* __restrict__ bias,
    const float* __restrict__ vin, float* __restrict__ vout)
{
    const int b  = blockIdx.x;     // 0..63
    const int t  = threadIdx.x;    // 0..255 (= k)
    const int c0 = b * 4;

    const float hv = vin[t];
    const float4 w = *reinterpret_cast<const float4*>(&W[(size_t)t * HID + c0]);
    float v[4] = {hv * w.x, hv * w.y, hv * w.z, hv * w.w};

    #pragma unroll
    for (int off = 32; off > 0; off >>= 1) {
        #pragma unroll
        for (int j = 0; j < 4; ++j) v[j] += __shfl_xor(v[j], off, 64);
    }

    __shared__ float lds[4][4];
    const int lane = t & 63, wid = t >> 6;
    if (lane == 0) {
        #pragma unroll
        for (int j = 0; j < 4; ++j) lds[wid][j] = v[j];
    }
    __syncthreads();
    if (t < 4) {
        const float a = lds[0][t] + lds[1][t] + lds[2][t] + lds[3][t];
        vout[c0 + t] = fmaxf(a + bias[c0 + t], 0.f);
    }
}

// ---- K4: L = o2 @ f3W + f3b; prob = softmax(L); one block --------------------
__global__ __launch_bounds__(256) void f3_softmax(
    const float* __restrict__ f3W, const float* __restrict__ f3b,
    float* __restrict__ ws)
{
    __shared__ float red[NOUT * 256];
    __shared__ float sL[NOUT];
    const int t = threadIdx.x;

    const float o2 = ws[WS_O2 + t];
    const float4 wlo = *reinterpret_cast<const float4*>(&f3W[(size_t)t * NOUT]);
    const float4 whi = *reinterpret_cast<const float4*>(&f3W[(size_t)t * NOUT + 4]);
    red[0*256+t] = o2*wlo.x; red[1*256+t] = o2*wlo.y;
    red[2*256+t] = o2*wlo.z; red[3*256+t] = o2*wlo.w;
    red[4*256+t] = o2*whi.x; red[5*256+t] = o2*whi.y;
    red[6*256+t] = o2*whi.z; red[7*256+t] = o2*whi.w;
    __syncthreads();
    for (int s = 128; s > 0; s >>= 1) {
        if (t < s) {
            #pragma unroll
            for (int j = 0; j < NOUT; ++j) red[j*256+t] += red[j*256+t+s];
        }
        __syncthreads();
    }
    if (t < NOUT) { sL[t] = red[t * 256] + f3b[t]; ws[t] = sL[t]; }
    __syncthreads();
    if (t == 0) {
        float m = sL[0];
        #pragma unroll
        for (int j = 1; j < NOUT; ++j) m = fmaxf(m, sL[j]);
        float e[NOUT], s = 0.f;
        #pragma unroll
        for (int j = 0; j < NOUT; ++j) { e[j] = expf(sL[j] - m); s += e[j]; }
        const float inv = 1.f / s;
        #pragma unroll
        for (int j = 0; j < NOUT; ++j) ws[NOUT + j] = e[j] * inv;
    }
}

// ---- K5: per-row gumbel softmax + broadcast prob -----------------------------
__global__ __launch_bounds__(256) void gumbel_kernel(
    const float* __restrict__ gn,  // [rows, 8] fp32
    const float* __restrict__ ws,  // L[8], prob[8]
    float* __restrict__ out,       // g_graph [rows,8] then prob [rows,8], fp32
    int rows)
{
    const int r = blockIdx.x * blockDim.x + threadIdx.x;
    if (r >= rows) return;

    float L[NOUT];
    #pragma unroll
    for (int j = 0; j < NOUT; ++j) L[j] = ws[j];

    const float4* gp = reinterpret_cast<const float4*>(gn + (size_t)r * NOUT);
    const float4 g0 = gp[0];
    const float4 g1 = gp[1];
    const float g[NOUT] = {g0.x, g0.y, g0.z, g0.w, g1.x, g1.y, g1.z, g1.w};

    float z[NOUT];
    float m = -1e30f;
    #pragma unroll
    for (int j = 0; j < NOUT; ++j) {
        z[j] = (L[j] + g[j]) * 2.0f;   // 1/TAU = 2
        m = fmaxf(m, z[j]);
    }
    float s = 0.f;
    #pragma unroll
    for (int j = 0; j < NOUT; ++j) { z[j] = expf(z[j] - m); s += z[j]; }
    const float inv = 1.f / s;

    float4* op = reinterpret_cast<float4*>(out + (size_t)r * NOUT);
    op[0] = make_float4(z[0]*inv, z[1]*inv, z[2]*inv, z[3]*inv);
    op[1] = make_float4(z[4]*inv, z[5]*inv, z[6]*inv, z[7]*inv);

    float4* pp = reinterpret_cast<float4*>(out + (size_t)(rows + r) * NOUT);
    pp[0] = make_float4(ws[8],  ws[9],  ws[10], ws[11]);
    pp[1] = make_float4(ws[12], ws[13], ws[14], ws[15]);
}

extern "C" void kernel_launch(void* const* d_in, const int* in_sizes, int n_in,
                              void* d_out, int out_size, void* d_ws, size_t ws_size,
                              hipStream_t stream) {
    // 0 graph, 1 rel_rec, 2 rel_send, 3 gumbel_noise,
    // 4 m1_W1, 5 m1_b1, 6 m1_W2, 7 m1_b2, 8 m1_g, 9 m1_beta,
    // 10 m2_W1, 11 m2_b1, 12 m2_W2, 13 m2_b2, 14 m2_g, 15 m2_beta,
    // 16 Wi, 17 bi, 18 Wn, 19 bn_b, 20 f1_W, 21 f1_b, 22 f2_W, 23 f2_b,
    // 24 f3_W, 25 f3_b
    const float* gumbel  = (const float*)d_in[3];
    const float* m2_beta = (const float*)d_in[15];
    const float* Wi      = (const float*)d_in[16];
    const float* bi      = (const float*)d_in[17];
    const float* Wn      = (const float*)d_in[18];
    const float* bn_b    = (const float*)d_in[19];
    const float* f1W     = (const float*)d_in[20];
    const float* f1b     = (const float*)d_in[21];
    const float* f2W     = (const float*)d_in[22];
    const float* f2b     = (const float*)d_in[23];
    const float* f3W     = (const float*)d_in[24];
    const float* f3b     = (const float*)d_in[25];

    const int rows = in_sizes[3] / NOUT;   // 260096
    float* ws = (float*)d_ws;

    gate_cols<<<64, 256, 0, stream>>>(m2_beta, Wi, Wn, bi, bn_b, ws);
    fc_cols<<<64, 256, 0, stream>>>(f1W, f1b, ws + WS_H,  ws + WS_O1);
    fc_cols<<<64, 256, 0, stream>>>(f2W, f2b, ws + WS_O1, ws + WS_O2);
    f3_softmax<<<1, 256, 0, stream>>>(f3W, f3b, ws);

    const int threads = 256;
    const int blocks = (rows + threads - 1) / threads;
    gumbel_kernel<<<blocks, threads, 0, stream>>>(gumbel, ws, (float*)d_out, rows);
}